// Round 12
// baseline (1778.483 us; speedup 1.0000x reference)
//
#include <hip/hip_runtime.h>

#define F_ 513
#define M_ 8
#define T_ 2048
#define K_ 2
#define NITER 20
#define REGC 1e-6f
#define EPSR 1e-10
#define TOLC 1e-5
#define NG 256
#define TS 4
#define UPB ((F_ + 3) / 4)

typedef double2 cd;
typedef float2 cf;
__device__ __forceinline__ cd cmk(double r, double i){ cd z; z.x=r; z.y=i; return z; }
__device__ __forceinline__ cf cmkf(float r, float i){ cf z; z.x=r; z.y=i; return z; }
__device__ __forceinline__ cf caddf(cf a, cf b){ return cmkf(a.x+b.x, a.y+b.y); }
__device__ __forceinline__ cf csubf(cf a, cf b){ return cmkf(a.x-b.x, a.y-b.y); }
__device__ __forceinline__ cf cmulf(cf a, cf b){ return cmkf(a.x*b.x - a.y*b.y, a.x*b.y + a.y*b.x); }
__device__ __forceinline__ cf cconjf(cf a){ return cmkf(a.x, -a.y); }
__device__ __forceinline__ cf cdivf(cf a, cf b){
  float d = b.x*b.x + b.y*b.y;
  return cmkf((a.x*b.x + a.y*b.y)/d, (a.y*b.x - a.x*b.y)/d);
}
__device__ __forceinline__ float cabs2f(cf a){ return a.x*a.x + a.y*a.y; }
__device__ __forceinline__ cf shflcf(cf v, int l){
  cf r; r.x = __shfl(v.x, l, 64); r.y = __shfl(v.y, l, 64); return r;
}
__device__ __forceinline__ cf sel8f(const cf x[8], int idx){
  cf r = x[0];
  #pragma unroll
  for (int q=1;q<8;++q) if (idx==q) r = x[q];
  return r;
}

// ---- per-f fp32 solve (wave-wide; lane=(i,j) of 8x8); V/C read from fp64 partials ----
__device__ __forceinline__ void solve_f32(int f, int lane,
    const cd* __restrict__ Vp, const cd* __restrict__ Cp,
    float2* __restrict__ Wg, double* __restrict__ dsum, double* __restrict__ osum)
{
  int i = lane >> 3, j = lane & 7;
  cf Wn = Wg[(size_t)f*64 + lane];
  cf Wold = Wn;
  cf x[8];
  #pragma unroll
  for (int k=0; k<K_; ++k){
    double vr=0, vi=0;
    #pragma unroll
    for (int s2=0; s2<TS; ++s2){
      cd v = Vp[(((size_t)k*F_ + f)*TS + s2)*64 + lane];
      vr += v.x; vi += v.y;
    }
    cf Vr = cmkf((float)vr, (float)vi);
    if (i == j) Vr.x += REGC;
    cf temp = cmkf(0.f,0.f);
    #pragma unroll
    for (int q=0;q<8;++q) temp = caddf(temp, cmulf(shflcf(Wn, i*8+q), shflcf(Vr, q*8+j)));
    cf b = cmkf(i==k ? 1.f : 0.f, 0.f);
    for (int p=0; p<8; ++p){
      // packed pivot argmax: float bits (non-negative) order-preserving; low 6 bits = row
      float pv = cabs2f(temp);
      unsigned pk = (j==p && i>=p) ? ((__float_as_uint(pv) & 0xFFFFFFC0u) | (unsigned)i) : 0u;
      #pragma unroll
      for (int off=32; off; off>>=1){
        unsigned o = __shfl_xor(pk, off, 64);
        if (o > pk) pk = o;
      }
      int pidx = (int)(pk & 63u);
      cf tp = shflcf(temp, pidx*8 + j);
      cf tq = shflcf(temp, p*8 + j);
      cf bp_ = shflcf(b, pidx*8 + j);
      cf bq_ = shflcf(b, p*8 + j);
      if (i == p){ temp = tp; b = bp_; }
      else if (i == pidx){ temp = tq; b = bq_; }
      cf tip = shflcf(temp, i*8 + p);
      cf tpp = shflcf(temp, p*8 + p);
      cf tpj = shflcf(temp, p*8 + j);
      cf bpr = shflcf(b, p*8 + j);
      cf fac = cdivf(tip, tpp);
      if (i > p){ temp = csubf(temp, cmulf(fac, tpj)); b = csubf(b, cmulf(fac, bpr)); }
    }
    #pragma unroll
    for (int p=7; p>=0; --p){
      cf s = shflcf(b, p*8);
      #pragma unroll
      for (int q=p+1; q<8; ++q){
        cf tpq = shflcf(temp, p*8 + q);
        s = csubf(s, cmulf(tpq, x[q]));
      }
      x[p] = cdivf(s, shflcf(temp, p*8 + p));
    }
    cf xi = sel8f(x, i), xj = sel8f(x, j);
    cf z = cmulf(cconjf(xi), Vr);
    float dl = z.x*xj.x - z.y*xj.y;
    #pragma unroll
    for (int off=32; off; off>>=1) dl += __shfl_xor(dl, off, 64);
    float denom = sqrtf(dl + 1e-10f);
    if (i == k){ Wn = cmkf(xj.x/denom, -xj.y/denom); }
  }
  double cr=0, ci=0;
  #pragma unroll
  for (int s2=0; s2<TS; ++s2){
    cd c = Cp[((size_t)f*TS + s2)*64 + lane];
    cr += c.x; ci += c.y;
  }
  cf Cc = cmkf((float)cr, (float)ci);
  cf tmp = cmkf(0.f,0.f);
  #pragma unroll
  for (int q=0;q<8;++q) tmp = caddf(tmp, cmulf(shflcf(Wn, i*8+q), shflcf(Cc, q*8+j)));
  cf A = shflcf(tmp, 0), B = shflcf(tmp, 1), C2 = shflcf(tmp, 8), D = shflcf(tmp, 9);
  cf det = csubf(cmulf(A,D), cmulf(B,C2));
  cf t0 = shflcf(tmp, i);
  cf t1 = shflcf(tmp, 8 + i);
  cf Z0 = cdivf(csubf(cmulf(D,t0), cmulf(B,t1)), det);
  cf Z1 = cdivf(csubf(cmulf(A,t1), cmulf(C2,t0)), det);
  if (i >= K_ && j < K_){
    cf Z = (j==0) ? Z0 : Z1;
    Wn = cconjf(Z);
  }
  cf dW = csubf(Wn, Wold);
  double ds = (double)dW.x*dW.x + (double)dW.y*dW.y;
  double os = (double)Wold.x*Wold.x + (double)Wold.y*Wold.y;
  #pragma unroll
  for (int off=32; off; off>>=1){
    ds += __shfl_xor(ds, off, 64);
    os += __shfl_xor(os, off, 64);
  }
  Wg[(size_t)f*64 + lane] = Wn;
  if (lane == 0){ dsum[f] = ds; osum[f] = os; }
}

// pack X (M,T,F,2) -> Xc (F,M,T) complex; 64f x 32t LDS tile
__global__ __launch_bounds__(256) void pack_kernel(const float2* __restrict__ Xin, float2* __restrict__ Xc){
  __shared__ float tr[32][65];
  __shared__ float ti[32][65];
  int f0 = blockIdx.x*64, t0 = blockIdx.y*32, m = blockIdx.z;
  for (int i = threadIdx.x; i < 32*64; i += 256){
    int tl = i >> 6, fl = i & 63;
    int f = f0 + fl;
    float2 v; v.x = 0.f; v.y = 0.f;
    if (f < F_) v = Xin[((size_t)m*T_ + (t0 + tl))*F_ + f];
    tr[tl][fl] = v.x; ti[tl][fl] = v.y;
  }
  __syncthreads();
  for (int i = threadIdx.x; i < 64*16; i += 256){
    int fl = i >> 4, tl2 = i & 15;
    int f = f0 + fl;
    if (f < F_){
      int t = 2*tl2;
      float4 v;
      v.x = tr[t][fl];   v.y = ti[t][fl];
      v.z = tr[t+1][fl]; v.w = ti[t+1][fl];
      *(float4*)&Xc[((size_t)f*8 + m)*T_ + t0 + t] = v;
    }
  }
}

// C chunk partials + fused W init. grid (F,TS), 512 thr.
__global__ __launch_bounds__(512) void cov0_kernel(const float2* __restrict__ Xc, cd* __restrict__ Cp,
                                                   float2* __restrict__ Wg){
  __shared__ float2 xs[8][514];
  __shared__ double wred[2][8][64];
  int f = blockIdx.x, s = blockIdx.y;
  int tid = threadIdx.x;
  int w = tid >> 6, lane = tid & 63;
  int m = lane >> 3, n = lane & 7;
  if (s == 0 && tid < 64){
    int i = tid >> 3, j = tid & 7;
    float v = (i==j) ? (i < K_ ? 1.f : -1.f) : 0.f;
    Wg[(size_t)f*64 + tid] = make_float2(v, 0.f);
  }
  #pragma unroll
  for (int r=0; r<4; ++r){
    int idx = tid + r*512;
    int mm = idx >> 8, q = idx & 255;
    float4 v = ((const float4*)(Xc + ((size_t)f*8 + mm)*T_ + s*512))[q];
    *(float4*)&xs[mm][q*2] = v;
  }
  __syncthreads();
  const float2* xm = xs[m];
  const float2* xn = xs[n];
  int tbase = w*64;
  float ar=0.f, ai=0.f;
  #pragma unroll 8
  for (int tt=0; tt<64; tt+=2){
    float4 av = *(const float4*)&xm[tbase+tt];
    float4 bv = *(const float4*)&xn[tbase+tt];
    ar += fmaf(av.x, bv.x, av.y*bv.y) + fmaf(av.z, bv.z, av.w*bv.w);
    ai += fmaf(av.y, bv.x, -av.x*bv.y) + fmaf(av.w, bv.z, -av.z*bv.w);
  }
  wred[0][w][lane] = ar; wred[1][w][lane] = ai;
  __syncthreads();
  if (tid < 64){
    double sr=0, si=0;
    #pragma unroll
    for (int ww=0; ww<8; ++ww){ sr += wred[0][ww][tid]; si += wred[1][ww][tid]; }
    const double inv = 1.0/(double)T_;
    Cp[((size_t)f*TS + s)*64 + tid] = cmk(sr*inv, si*inv);
  }
}

// partial r2 over f-groups: grid (T_/256, NG); part[g][k][t]
__global__ __launch_bounds__(256) void yr_kernel(const float2* __restrict__ Xc, const float2* __restrict__ Wg,
                                                 float* __restrict__ part, const int* __restrict__ flags){
  if (*(volatile const int*)flags) return;
  int g = blockIdx.y;
  int t = blockIdx.x*256 + threadIdx.x;
  float acc0 = 0.f, acc1 = 0.f;
  for (int f = g; f < F_; f += NG){
    const float2* Wf = Wg + (size_t)f*64;
    float2 y0; y0.x=0; y0.y=0;
    float2 y1; y1.x=0; y1.y=0;
    #pragma unroll
    for (int m=0;m<8;++m){
      float2 xv = Xc[((size_t)f*8 + m)*T_ + t];
      float2 w0 = Wf[m];
      float2 w1 = Wf[8+m];
      y0.x = fmaf(w0.x,xv.x,fmaf(-w0.y,xv.y,y0.x)); y0.y = fmaf(w0.x,xv.y,fmaf(w0.y,xv.x,y0.y));
      y1.x = fmaf(w1.x,xv.x,fmaf(-w1.y,xv.y,y1.x)); y1.y = fmaf(w1.x,xv.y,fmaf(w1.y,xv.x,y1.y));
    }
    acc0 += y0.x*y0.x + y0.y*y0.y;
    acc1 += y1.x*y1.x + y1.y*y1.y;
  }
  part[((size_t)g*2+0)*T_ + t] = acc0;
  part[((size_t)g*2+1)*T_ + t] = acc1;
}

// wts2f[2t+k]: grid 64 blocks x 256 thr; 4-way g-split + LDS reduce (deterministic order)
__global__ __launch_bounds__(256) void rw_kernel(const float* __restrict__ part, float* __restrict__ wts2f,
                                                 const int* __restrict__ flags){
  if (*(volatile const int*)flags) return;
  __shared__ double red[4][64];
  int l = threadIdx.x & 63, s = threadIdx.x >> 6;
  int v = blockIdx.x*64 + l;
  int k = v >> 11, t = v & (T_-1);
  double sum = 0;
  for (int g=s; g<NG; g+=4) sum += (double)part[((size_t)g*2+k)*T_ + t];
  red[s][l] = sum;
  __syncthreads();
  if (threadIdx.x < 64){
    double tot = red[0][l] + red[1][l] + red[2][l] + red[3][l];
    wts2f[2*t + k] = (float)(0.5 / sqrt(fmax(tot, EPSR)));
  }
}

// V partials only. grid (F_, TS), block 512 (8 waves).
__global__ __launch_bounds__(512, 8) void covF_kernel(const float2* __restrict__ Xc, const float2* __restrict__ wts2,
                                                      cd* __restrict__ Vp, const int* __restrict__ flags){
  if (*(volatile const int*)flags) return;
  __shared__ float2 xs[8][514];
  __shared__ float2 wsm2[512];
  int f = blockIdx.x, s = blockIdx.y;
  int tid = threadIdx.x;
  int w = tid >> 6, lane = tid & 63;
  int m = lane >> 3, n = lane & 7;
  #pragma unroll
  for (int r=0; r<4; ++r){
    int idx = tid + r*512;
    int mm = idx >> 8, q = idx & 255;
    float4 v = ((const float4*)(Xc + ((size_t)f*8 + mm)*T_ + s*512))[q];
    *(float4*)&xs[mm][q*2] = v;
  }
  wsm2[tid] = wts2[s*512 + tid];
  __syncthreads();
  const float2* xm = xs[m];
  const float2* xn = xs[n];
  int tbase = w*64;
  float a0r=0.f, a0i=0.f, a1r=0.f, a1i=0.f;
  #pragma unroll 8
  for (int tt=0; tt<64; tt+=2){
    float4 av = *(const float4*)&xm[tbase+tt];
    float4 bv = *(const float4*)&xn[tbase+tt];
    float zr0 = fmaf(av.x, bv.x, av.y*bv.y);
    float zi0 = fmaf(av.y, bv.x, -av.x*bv.y);
    float zr1 = fmaf(av.z, bv.z, av.w*bv.w);
    float zi1 = fmaf(av.w, bv.z, -av.z*bv.w);
    float4 wv = *(const float4*)&wsm2[tbase+tt];
    a0r = fmaf(wv.x, zr0, a0r); a0i = fmaf(wv.x, zi0, a0i);
    a1r = fmaf(wv.y, zr0, a1r); a1i = fmaf(wv.y, zi0, a1i);
    a0r = fmaf(wv.z, zr1, a0r); a0i = fmaf(wv.z, zi1, a0i);
    a1r = fmaf(wv.w, zr1, a1r); a1i = fmaf(wv.w, zi1, a1i);
  }
  __syncthreads();
  float* wred = (float*)&xs[0][0];
  wred[0*512 + w*64 + lane] = a0r;
  wred[1*512 + w*64 + lane] = a0i;
  wred[2*512 + w*64 + lane] = a1r;
  wred[3*512 + w*64 + lane] = a1i;
  __syncthreads();
  const double inv = 1.0/(double)T_;
  if (tid < 128){
    int k = tid >> 6, l = tid & 63;
    float rr = 0.f, ii = 0.f;
    #pragma unroll
    for (int ww=0; ww<8; ++ww){
      rr += wred[(k*2+0)*512 + ww*64 + l];
      ii += wred[(k*2+1)*512 + ww*64 + l];
    }
    Vp[(((size_t)k*F_ + f)*TS + s)*64 + l] = cmk((double)rr*inv, (double)ii*inv);
  }
}

// solve kernel: 4 waves/block, one f per wave; fused convergence ticket
__global__ __launch_bounds__(256) void updF_kernel(const cd* __restrict__ Vp, const cd* __restrict__ Cp,
                                                   float2* __restrict__ Wg,
                                                   double* __restrict__ dsum, double* __restrict__ osum,
                                                   int* __restrict__ flags){
  if (*(volatile const int*)flags) return;
  int lane = threadIdx.x & 63;
  int w = threadIdx.x >> 6;
  int f = blockIdx.x*4 + w;
  if (f < F_) solve_f32(f, lane, Vp, Cp, Wg, dsum, osum);
  __shared__ int lastFlag;
  __threadfence();
  __syncthreads();
  if (threadIdx.x == 0){
    int tk = atomicAdd(&flags[1], 1);
    lastFlag = (tk == UPB-1) ? 1 : 0;
  }
  __syncthreads();
  if (lastFlag && threadIdx.x < 64){
    __threadfence();
    double d=0, o=0;
    for (int idx=lane; idx<F_; idx+=64){
      d += ((volatile double*)dsum)[idx];
      o += ((volatile double*)osum)[idx];
    }
    for (int off=32; off; off>>=1){ d += __shfl_xor(d, off, 64); o += __shfl_xor(o, off, 64); }
    if (lane == 0){
      flags[1] = 0;
      double rel = sqrt(d) / fmax(sqrt(o), 1.1920928955078125e-7);
      if (rel < TOLC) flags[0] = 1;
    }
  }
}

// out (K,T,F,2) with fused MDP scale, via LDS transpose. grid (17, 32)
__global__ __launch_bounds__(256) void out_kernel(const float2* __restrict__ Xc, const float2* __restrict__ Wg,
                                                  float2* __restrict__ out){
  __shared__ float re0[32][65], im0[32][65], re1[32][65], im1[32][65];
  __shared__ float2 scl[32][2];
  int f0 = blockIdx.x*32, t0 = blockIdx.y*64;
  int lane = threadIdx.x & 63, w = threadIdx.x >> 6;
  if (threadIdx.x < 32){
    int f = f0 + threadIdx.x;
    if (f < F_){
      cd w0[8], w1[8];
      #pragma unroll
      for (int m=0;m<8;++m){
        float2 a = Wg[(size_t)f*64 + m];     w0[m] = cmk(a.x, a.y);
        float2 b = Wg[(size_t)f*64 + 8 + m]; w1[m] = cmk(b.x, b.y);
      }
      cd G00 = cmk(0,0), G01 = cmk(0,0), G11 = cmk(0,0);
      #pragma unroll
      for (int m=0;m<8;++m){
        G00.x += w0[m].x*w0[m].x + w0[m].y*w0[m].y;
        G01.x += w0[m].x*w1[m].x + w0[m].y*w1[m].y;
        G01.y += w0[m].y*w1[m].x - w0[m].x*w1[m].y;
        G11.x += w1[m].x*w1[m].x + w1[m].y*w1[m].y;
      }
      cd det; det.x = G00.x*G11.x - (G01.x*G01.x + G01.y*G01.y); det.y = 0.0;
      // inv(G) = [[G11, -G01],[-conj(G01), G00]] / det   (G Hermitian, det real)
      double idet = 1.0 / det.x;
      cd I00 = cmk(G11.x*idet, 0.0);
      cd I01 = cmk(-G01.x*idet, -G01.y*idet);
      cd I10 = cmk(-G01.x*idet,  G01.y*idet);
      cd I11 = cmk(G00.x*idet, 0.0);
      cd c0 = cmk(w0[0].x, -w0[0].y), c1 = cmk(w1[0].x, -w1[0].y);
      cd s0 = cmk(c0.x*I00.x - c0.y*I00.y + c1.x*I10.x - c1.y*I10.y,
                  c0.x*I00.y + c0.y*I00.x + c1.x*I10.y + c1.y*I10.x);
      cd s1 = cmk(c0.x*I01.x - c0.y*I01.y + c1.x*I11.x - c1.y*I11.y,
                  c0.x*I01.y + c0.y*I01.x + c1.x*I11.y + c1.y*I11.x);
      scl[threadIdx.x][0] = make_float2((float)s0.x, (float)s0.y);
      scl[threadIdx.x][1] = make_float2((float)s1.x, (float)s1.y);
    }
  }
  __syncthreads();
  for (int fl = w; fl < 32; fl += 4){
    int f = f0 + fl;
    if (f < F_){
      const float2* Wf = Wg + (size_t)f*64;
      int t = t0 + lane;
      float2 y0; y0.x=0; y0.y=0;
      float2 y1; y1.x=0; y1.y=0;
      #pragma unroll
      for (int m=0;m<8;++m){
        float2 xv = Xc[((size_t)f*8 + m)*T_ + t];
        float2 w0 = Wf[m];
        float2 w1 = Wf[8+m];
        y0.x += w0.x*xv.x - w0.y*xv.y; y0.y += w0.x*xv.y + w0.y*xv.x;
        y1.x += w1.x*xv.x - w1.y*xv.y; y1.y += w1.x*xv.y + w1.y*xv.x;
      }
      float2 s0 = scl[fl][0];
      float2 s1 = scl[fl][1];
      re0[fl][lane] = s0.x*y0.x - s0.y*y0.y; im0[fl][lane] = s0.x*y0.y + s0.y*y0.x;
      re1[fl][lane] = s1.x*y1.x - s1.y*y1.y; im1[fl][lane] = s1.x*y1.y + s1.y*y1.x;
    }
  }
  __syncthreads();
  for (int i = threadIdx.x; i < 32*64; i += 256){
    int tl = i >> 5, fl = i & 31;
    int f = f0 + fl;
    if (f < F_){
      int t = t0 + tl;
      float2 o0; o0.x = re0[fl][tl]; o0.y = im0[fl][tl];
      float2 o1; o1.x = re1[fl][tl]; o1.y = im1[fl][tl];
      out[((size_t)(0*T_ + t))*F_ + f] = o0;
      out[((size_t)(1*T_ + t))*F_ + f] = o1;
    }
  }
}

extern "C" void kernel_launch(void* const* d_in, const int* in_sizes, int n_in,
                              void* d_out, int out_size, void* d_ws, size_t ws_size,
                              hipStream_t stream) {
  const float2* Xin = (const float2*)d_in[0];
  char* ws = (char*)d_ws;
  size_t off = 0;
  auto alloc = [&](size_t bytes) -> void* {
    void* p = ws + off;
    off += (bytes + 255) & ~(size_t)255;
    return p;
  };
  float2* Xc   = (float2*)alloc((size_t)F_*M_*T_*8);
  cd*     Cp   = (cd*)alloc((size_t)F_*TS*64*16);
  cd*     Vp   = (cd*)alloc((size_t)K_*F_*TS*64*16);
  float2* W    = (float2*)alloc((size_t)F_*64*8);
  float*  part = (float*)alloc((size_t)NG*K_*T_*4);
  float*  wts2 = (float*)alloc((size_t)T_*8);
  double* dsum = (double*)alloc((size_t)F_*8);
  double* osum = (double*)alloc((size_t)F_*8);
  int*    ibuf = (int*)alloc(4096);
  if (off > ws_size) return;
  int* flags = ibuf;          // [0]=done, [1]=solve convergence ticket

  hipMemsetAsync(ibuf, 0, 4096, stream);

  pack_kernel<<<dim3(9, 64, 8), 256, 0, stream>>>(Xin, Xc);
  cov0_kernel<<<dim3(F_, TS), 512, 0, stream>>>(Xc, Cp, W);

  for (int it=0; it<NITER; ++it){
    yr_kernel<<<dim3(T_/256, NG), 256, 0, stream>>>(Xc, W, part, flags);
    rw_kernel<<<64, 256, 0, stream>>>(part, wts2, flags);
    covF_kernel<<<dim3(F_, TS), 512, 0, stream>>>(Xc, (const float2*)wts2, Vp, flags);
    updF_kernel<<<UPB, 256, 0, stream>>>(Vp, Cp, W, dsum, osum, flags);
  }

  out_kernel<<<dim3(17, 32), 256, 0, stream>>>(Xc, W, (float2*)d_out);
}

// Round 13
// 1639.444 us; speedup vs baseline: 1.0848x; 1.0848x over previous
//
#include <hip/hip_runtime.h>

#define F_ 513
#define M_ 8
#define T_ 2048
#define K_ 2
#define NITER 20
#define REGC 1e-6f
#define EPSR 1e-10
#define TOLC 1e-5
#define NG 256
#define TS 4
#define UPB ((F_ + 3) / 4)

typedef double2 cd;
typedef float2 cf;
__device__ __forceinline__ cd cmk(double r, double i){ cd z; z.x=r; z.y=i; return z; }
__device__ __forceinline__ cf cmkf(float r, float i){ cf z; z.x=r; z.y=i; return z; }
__device__ __forceinline__ cf caddf(cf a, cf b){ return cmkf(a.x+b.x, a.y+b.y); }
__device__ __forceinline__ cf csubf(cf a, cf b){ return cmkf(a.x-b.x, a.y-b.y); }
__device__ __forceinline__ cf cmulf(cf a, cf b){ return cmkf(a.x*b.x - a.y*b.y, a.x*b.y + a.y*b.x); }
__device__ __forceinline__ cf cconjf(cf a){ return cmkf(a.x, -a.y); }
__device__ __forceinline__ cf cdivf(cf a, cf b){
  float d = b.x*b.x + b.y*b.y;
  return cmkf((a.x*b.x + a.y*b.y)/d, (a.y*b.x - a.x*b.y)/d);
}
__device__ __forceinline__ float cabs2f(cf a){ return a.x*a.x + a.y*a.y; }
__device__ __forceinline__ cf shflcf(cf v, int l){
  cf r; r.x = __shfl(v.x, l, 64); r.y = __shfl(v.y, l, 64); return r;
}

// ---- per-f fp32 solve (wave-wide; lane=(i,j) of 8x8); array-free (registers only) ----
__device__ __forceinline__ void solve_f32(int f, int lane,
    const cd* __restrict__ Vp, const cd* __restrict__ Cp,
    float2* __restrict__ Wg, double* __restrict__ dsum, double* __restrict__ osum)
{
  int i = lane >> 3, j = lane & 7;
  cf Wn = Wg[(size_t)f*64 + lane];
  cf Wold = Wn;
  #pragma unroll
  for (int k=0; k<K_; ++k){
    double vr=0, vi=0;
    #pragma unroll
    for (int s2=0; s2<TS; ++s2){
      cd v = Vp[(((size_t)k*F_ + f)*TS + s2)*64 + lane];
      vr += v.x; vi += v.y;
    }
    cf Vr = cmkf((float)vr, (float)vi);
    if (i == j) Vr.x += REGC;
    cf temp = cmkf(0.f,0.f);
    #pragma unroll
    for (int q=0;q<8;++q) temp = caddf(temp, cmulf(shflcf(Wn, i*8+q), shflcf(Vr, q*8+j)));
    cf b = cmkf(i==k ? 1.f : 0.f, 0.f);
    #pragma unroll 1
    for (int p=0; p<8; ++p){
      // packed pivot argmax: float bits (non-negative) order-preserving; low 6 bits = row
      float pv = cabs2f(temp);
      unsigned pk = (j==p && i>=p) ? ((__float_as_uint(pv) & 0xFFFFFFC0u) | (unsigned)i) : 0u;
      #pragma unroll
      for (int off=32; off; off>>=1){
        unsigned o = __shfl_xor(pk, off, 64);
        if (o > pk) pk = o;
      }
      int pidx = (int)(pk & 63u);
      cf tp = shflcf(temp, pidx*8 + j);
      cf tq = shflcf(temp, p*8 + j);
      cf bp_ = shflcf(b, pidx*8 + j);
      cf bq_ = shflcf(b, p*8 + j);
      if (i == p){ temp = tp; b = bp_; }
      else if (i == pidx){ temp = tq; b = bq_; }
      cf tip = shflcf(temp, i*8 + p);
      cf tpp = shflcf(temp, p*8 + p);
      cf tpj = shflcf(temp, p*8 + j);
      cf bpr = shflcf(b, p*8 + j);
      cf fac = cdivf(tip, tpp);
      if (i > p){ temp = csubf(temp, cmulf(fac, tpj)); b = csubf(b, cmulf(fac, bpr)); }
    }
    // ---- back substitution with named scalars (no arrays -> stays in VGPRs) ----
    cf x7, x6, x5, x4, x3, x2, x1, x0, s;
    x7 = cdivf(shflcf(b,56), shflcf(temp,63));
    s  = csubf(shflcf(b,48), cmulf(shflcf(temp,55),x7));
    x6 = cdivf(s, shflcf(temp,54));
    s  = csubf(shflcf(b,40), cmulf(shflcf(temp,47),x7));
    s  = csubf(s, cmulf(shflcf(temp,46),x6));
    x5 = cdivf(s, shflcf(temp,45));
    s  = csubf(shflcf(b,32), cmulf(shflcf(temp,39),x7));
    s  = csubf(s, cmulf(shflcf(temp,38),x6));
    s  = csubf(s, cmulf(shflcf(temp,37),x5));
    x4 = cdivf(s, shflcf(temp,36));
    s  = csubf(shflcf(b,24), cmulf(shflcf(temp,31),x7));
    s  = csubf(s, cmulf(shflcf(temp,30),x6));
    s  = csubf(s, cmulf(shflcf(temp,29),x5));
    s  = csubf(s, cmulf(shflcf(temp,28),x4));
    x3 = cdivf(s, shflcf(temp,27));
    s  = csubf(shflcf(b,16), cmulf(shflcf(temp,23),x7));
    s  = csubf(s, cmulf(shflcf(temp,22),x6));
    s  = csubf(s, cmulf(shflcf(temp,21),x5));
    s  = csubf(s, cmulf(shflcf(temp,20),x4));
    s  = csubf(s, cmulf(shflcf(temp,19),x3));
    x2 = cdivf(s, shflcf(temp,18));
    s  = csubf(shflcf(b,8),  cmulf(shflcf(temp,15),x7));
    s  = csubf(s, cmulf(shflcf(temp,14),x6));
    s  = csubf(s, cmulf(shflcf(temp,13),x5));
    s  = csubf(s, cmulf(shflcf(temp,12),x4));
    s  = csubf(s, cmulf(shflcf(temp,11),x3));
    s  = csubf(s, cmulf(shflcf(temp,10),x2));
    x1 = cdivf(s, shflcf(temp,9));
    s  = csubf(shflcf(b,0),  cmulf(shflcf(temp,7),x7));
    s  = csubf(s, cmulf(shflcf(temp,6),x6));
    s  = csubf(s, cmulf(shflcf(temp,5),x5));
    s  = csubf(s, cmulf(shflcf(temp,4),x4));
    s  = csubf(s, cmulf(shflcf(temp,3),x3));
    s  = csubf(s, cmulf(shflcf(temp,2),x2));
    s  = csubf(s, cmulf(shflcf(temp,1),x1));
    x0 = cdivf(s, shflcf(temp,0));
    // select xi (by i) and xj (by j) via cndmask chains
    cf xi = x0;
    if (i==1) xi = x1; if (i==2) xi = x2; if (i==3) xi = x3;
    if (i==4) xi = x4; if (i==5) xi = x5; if (i==6) xi = x6; if (i==7) xi = x7;
    cf xj = x0;
    if (j==1) xj = x1; if (j==2) xj = x2; if (j==3) xj = x3;
    if (j==4) xj = x4; if (j==5) xj = x5; if (j==6) xj = x6; if (j==7) xj = x7;
    cf z = cmulf(cconjf(xi), Vr);
    float dl = z.x*xj.x - z.y*xj.y;
    #pragma unroll
    for (int off=32; off; off>>=1) dl += __shfl_xor(dl, off, 64);
    float denom = sqrtf(dl + 1e-10f);
    if (i == k){ Wn = cmkf(xj.x/denom, -xj.y/denom); }
  }
  double cr=0, ci=0;
  #pragma unroll
  for (int s2=0; s2<TS; ++s2){
    cd c = Cp[((size_t)f*TS + s2)*64 + lane];
    cr += c.x; ci += c.y;
  }
  cf Cc = cmkf((float)cr, (float)ci);
  cf tmp = cmkf(0.f,0.f);
  #pragma unroll
  for (int q=0;q<8;++q) tmp = caddf(tmp, cmulf(shflcf(Wn, i*8+q), shflcf(Cc, q*8+j)));
  cf A = shflcf(tmp, 0), B = shflcf(tmp, 1), C2 = shflcf(tmp, 8), D = shflcf(tmp, 9);
  cf det = csubf(cmulf(A,D), cmulf(B,C2));
  cf t0 = shflcf(tmp, i);
  cf t1 = shflcf(tmp, 8 + i);
  cf Z0 = cdivf(csubf(cmulf(D,t0), cmulf(B,t1)), det);
  cf Z1 = cdivf(csubf(cmulf(A,t1), cmulf(C2,t0)), det);
  if (i >= K_ && j < K_){
    cf Z = (j==0) ? Z0 : Z1;
    Wn = cconjf(Z);
  }
  cf dW = csubf(Wn, Wold);
  double ds = (double)dW.x*dW.x + (double)dW.y*dW.y;
  double os = (double)Wold.x*Wold.x + (double)Wold.y*Wold.y;
  #pragma unroll
  for (int off=32; off; off>>=1){
    ds += __shfl_xor(ds, off, 64);
    os += __shfl_xor(os, off, 64);
  }
  Wg[(size_t)f*64 + lane] = Wn;
  if (lane == 0){ dsum[f] = ds; osum[f] = os; }
}

// pack X (M,T,F,2) -> Xc (F,M,T) complex; 64f x 32t LDS tile
__global__ __launch_bounds__(256) void pack_kernel(const float2* __restrict__ Xin, float2* __restrict__ Xc){
  __shared__ float tr[32][65];
  __shared__ float ti[32][65];
  int f0 = blockIdx.x*64, t0 = blockIdx.y*32, m = blockIdx.z;
  for (int i = threadIdx.x; i < 32*64; i += 256){
    int tl = i >> 6, fl = i & 63;
    int f = f0 + fl;
    float2 v; v.x = 0.f; v.y = 0.f;
    if (f < F_) v = Xin[((size_t)m*T_ + (t0 + tl))*F_ + f];
    tr[tl][fl] = v.x; ti[tl][fl] = v.y;
  }
  __syncthreads();
  for (int i = threadIdx.x; i < 64*16; i += 256){
    int fl = i >> 4, tl2 = i & 15;
    int f = f0 + fl;
    if (f < F_){
      int t = 2*tl2;
      float4 v;
      v.x = tr[t][fl];   v.y = ti[t][fl];
      v.z = tr[t+1][fl]; v.w = ti[t+1][fl];
      *(float4*)&Xc[((size_t)f*8 + m)*T_ + t0 + t] = v;
    }
  }
}

// C chunk partials + fused W init. grid (F,TS), 512 thr.
__global__ __launch_bounds__(512) void cov0_kernel(const float2* __restrict__ Xc, cd* __restrict__ Cp,
                                                   float2* __restrict__ Wg){
  __shared__ float2 xs[8][514];
  __shared__ double wred[2][8][64];
  int f = blockIdx.x, s = blockIdx.y;
  int tid = threadIdx.x;
  int w = tid >> 6, lane = tid & 63;
  int m = lane >> 3, n = lane & 7;
  if (s == 0 && tid < 64){
    int i = tid >> 3, j = tid & 7;
    float v = (i==j) ? (i < K_ ? 1.f : -1.f) : 0.f;
    Wg[(size_t)f*64 + tid] = make_float2(v, 0.f);
  }
  #pragma unroll
  for (int r=0; r<4; ++r){
    int idx = tid + r*512;
    int mm = idx >> 8, q = idx & 255;
    float4 v = ((const float4*)(Xc + ((size_t)f*8 + mm)*T_ + s*512))[q];
    *(float4*)&xs[mm][q*2] = v;
  }
  __syncthreads();
  const float2* xm = xs[m];
  const float2* xn = xs[n];
  int tbase = w*64;
  float ar=0.f, ai=0.f;
  #pragma unroll 8
  for (int tt=0; tt<64; tt+=2){
    float4 av = *(const float4*)&xm[tbase+tt];
    float4 bv = *(const float4*)&xn[tbase+tt];
    ar += fmaf(av.x, bv.x, av.y*bv.y) + fmaf(av.z, bv.z, av.w*bv.w);
    ai += fmaf(av.y, bv.x, -av.x*bv.y) + fmaf(av.w, bv.z, -av.z*bv.w);
  }
  wred[0][w][lane] = ar; wred[1][w][lane] = ai;
  __syncthreads();
  if (tid < 64){
    double sr=0, si=0;
    #pragma unroll
    for (int ww=0; ww<8; ++ww){ sr += wred[0][ww][tid]; si += wred[1][ww][tid]; }
    const double inv = 1.0/(double)T_;
    Cp[((size_t)f*TS + s)*64 + tid] = cmk(sr*inv, si*inv);
  }
}

// partial r2 over f-groups: grid (T_/256, NG); part[g][k][t]
__global__ __launch_bounds__(256) void yr_kernel(const float2* __restrict__ Xc, const float2* __restrict__ Wg,
                                                 float* __restrict__ part, const int* __restrict__ flags){
  if (*(volatile const int*)flags) return;
  int g = blockIdx.y;
  int t = blockIdx.x*256 + threadIdx.x;
  float acc0 = 0.f, acc1 = 0.f;
  for (int f = g; f < F_; f += NG){
    const float2* Wf = Wg + (size_t)f*64;
    float2 y0; y0.x=0; y0.y=0;
    float2 y1; y1.x=0; y1.y=0;
    #pragma unroll
    for (int m=0;m<8;++m){
      float2 xv = Xc[((size_t)f*8 + m)*T_ + t];
      float2 w0 = Wf[m];
      float2 w1 = Wf[8+m];
      y0.x = fmaf(w0.x,xv.x,fmaf(-w0.y,xv.y,y0.x)); y0.y = fmaf(w0.x,xv.y,fmaf(w0.y,xv.x,y0.y));
      y1.x = fmaf(w1.x,xv.x,fmaf(-w1.y,xv.y,y1.x)); y1.y = fmaf(w1.x,xv.y,fmaf(w1.y,xv.x,y1.y));
    }
    acc0 += y0.x*y0.x + y0.y*y0.y;
    acc1 += y1.x*y1.x + y1.y*y1.y;
  }
  part[((size_t)g*2+0)*T_ + t] = acc0;
  part[((size_t)g*2+1)*T_ + t] = acc1;
}

// wts2f[2t+k]: grid 64 blocks x 256 thr; 4-way g-split + LDS reduce (deterministic order)
__global__ __launch_bounds__(256) void rw_kernel(const float* __restrict__ part, float* __restrict__ wts2f,
                                                 const int* __restrict__ flags){
  if (*(volatile const int*)flags) return;
  __shared__ double red[4][64];
  int l = threadIdx.x & 63, s = threadIdx.x >> 6;
  int v = blockIdx.x*64 + l;
  int k = v >> 11, t = v & (T_-1);
  double sum = 0;
  for (int g=s; g<NG; g+=4) sum += (double)part[((size_t)g*2+k)*T_ + t];
  red[s][l] = sum;
  __syncthreads();
  if (threadIdx.x < 64){
    double tot = red[0][l] + red[1][l] + red[2][l] + red[3][l];
    wts2f[2*t + k] = (float)(0.5 / sqrt(fmax(tot, EPSR)));
  }
}

// V partials only. grid (F_, TS), block 512 (8 waves).
__global__ __launch_bounds__(512, 8) void covF_kernel(const float2* __restrict__ Xc, const float2* __restrict__ wts2,
                                                      cd* __restrict__ Vp, const int* __restrict__ flags){
  if (*(volatile const int*)flags) return;
  __shared__ float2 xs[8][514];
  __shared__ float2 wsm2[512];
  int f = blockIdx.x, s = blockIdx.y;
  int tid = threadIdx.x;
  int w = tid >> 6, lane = tid & 63;
  int m = lane >> 3, n = lane & 7;
  #pragma unroll
  for (int r=0; r<4; ++r){
    int idx = tid + r*512;
    int mm = idx >> 8, q = idx & 255;
    float4 v = ((const float4*)(Xc + ((size_t)f*8 + mm)*T_ + s*512))[q];
    *(float4*)&xs[mm][q*2] = v;
  }
  wsm2[tid] = wts2[s*512 + tid];
  __syncthreads();
  const float2* xm = xs[m];
  const float2* xn = xs[n];
  int tbase = w*64;
  float a0r=0.f, a0i=0.f, a1r=0.f, a1i=0.f;
  #pragma unroll 8
  for (int tt=0; tt<64; tt+=2){
    float4 av = *(const float4*)&xm[tbase+tt];
    float4 bv = *(const float4*)&xn[tbase+tt];
    float zr0 = fmaf(av.x, bv.x, av.y*bv.y);
    float zi0 = fmaf(av.y, bv.x, -av.x*bv.y);
    float zr1 = fmaf(av.z, bv.z, av.w*bv.w);
    float zi1 = fmaf(av.w, bv.z, -av.z*bv.w);
    float4 wv = *(const float4*)&wsm2[tbase+tt];
    a0r = fmaf(wv.x, zr0, a0r); a0i = fmaf(wv.x, zi0, a0i);
    a1r = fmaf(wv.y, zr0, a1r); a1i = fmaf(wv.y, zi0, a1i);
    a0r = fmaf(wv.z, zr1, a0r); a0i = fmaf(wv.z, zi1, a0i);
    a1r = fmaf(wv.w, zr1, a1r); a1i = fmaf(wv.w, zi1, a1i);
  }
  __syncthreads();
  float* wred = (float*)&xs[0][0];
  wred[0*512 + w*64 + lane] = a0r;
  wred[1*512 + w*64 + lane] = a0i;
  wred[2*512 + w*64 + lane] = a1r;
  wred[3*512 + w*64 + lane] = a1i;
  __syncthreads();
  const double inv = 1.0/(double)T_;
  if (tid < 128){
    int k = tid >> 6, l = tid & 63;
    float rr = 0.f, ii = 0.f;
    #pragma unroll
    for (int ww=0; ww<8; ++ww){
      rr += wred[(k*2+0)*512 + ww*64 + l];
      ii += wred[(k*2+1)*512 + ww*64 + l];
    }
    Vp[(((size_t)k*F_ + f)*TS + s)*64 + l] = cmk((double)rr*inv, (double)ii*inv);
  }
}

// solve kernel: 4 waves/block, one f per wave; fused convergence ticket
__global__ __launch_bounds__(256) void updF_kernel(const cd* __restrict__ Vp, const cd* __restrict__ Cp,
                                                   float2* __restrict__ Wg,
                                                   double* __restrict__ dsum, double* __restrict__ osum,
                                                   int* __restrict__ flags){
  if (*(volatile const int*)flags) return;
  int lane = threadIdx.x & 63;
  int w = threadIdx.x >> 6;
  int f = blockIdx.x*4 + w;
  if (f < F_) solve_f32(f, lane, Vp, Cp, Wg, dsum, osum);
  __shared__ int lastFlag;
  __threadfence();
  __syncthreads();
  if (threadIdx.x == 0){
    int tk = atomicAdd(&flags[1], 1);
    lastFlag = (tk == UPB-1) ? 1 : 0;
  }
  __syncthreads();
  if (lastFlag && threadIdx.x < 64){
    __threadfence();
    double d=0, o=0;
    for (int idx=lane; idx<F_; idx+=64){
      d += ((volatile double*)dsum)[idx];
      o += ((volatile double*)osum)[idx];
    }
    for (int off=32; off; off>>=1){ d += __shfl_xor(d, off, 64); o += __shfl_xor(o, off, 64); }
    if (lane == 0){
      flags[1] = 0;
      double rel = sqrt(d) / fmax(sqrt(o), 1.1920928955078125e-7);
      if (rel < TOLC) flags[0] = 1;
    }
  }
}

// out (K,T,F,2) with fused MDP scale, via LDS transpose. grid (17, 32)
__global__ __launch_bounds__(256) void out_kernel(const float2* __restrict__ Xc, const float2* __restrict__ Wg,
                                                  float2* __restrict__ out){
  __shared__ float re0[32][65], im0[32][65], re1[32][65], im1[32][65];
  __shared__ float2 scl[32][2];
  int f0 = blockIdx.x*32, t0 = blockIdx.y*64;
  int lane = threadIdx.x & 63, w = threadIdx.x >> 6;
  if (threadIdx.x < 32){
    int f = f0 + threadIdx.x;
    if (f < F_){
      cd w0[8], w1[8];
      #pragma unroll
      for (int m=0;m<8;++m){
        float2 a = Wg[(size_t)f*64 + m];     w0[m] = cmk(a.x, a.y);
        float2 b = Wg[(size_t)f*64 + 8 + m]; w1[m] = cmk(b.x, b.y);
      }
      cd G00 = cmk(0,0), G01 = cmk(0,0), G11 = cmk(0,0);
      #pragma unroll
      for (int m=0;m<8;++m){
        G00.x += w0[m].x*w0[m].x + w0[m].y*w0[m].y;
        G01.x += w0[m].x*w1[m].x + w0[m].y*w1[m].y;
        G01.y += w0[m].y*w1[m].x - w0[m].x*w1[m].y;
        G11.x += w1[m].x*w1[m].x + w1[m].y*w1[m].y;
      }
      double det = G00.x*G11.x - (G01.x*G01.x + G01.y*G01.y);
      double idet = 1.0 / det;
      cd I00 = cmk(G11.x*idet, 0.0);
      cd I01 = cmk(-G01.x*idet, -G01.y*idet);
      cd I10 = cmk(-G01.x*idet,  G01.y*idet);
      cd I11 = cmk(G00.x*idet, 0.0);
      cd c0 = cmk(w0[0].x, -w0[0].y), c1 = cmk(w1[0].x, -w1[0].y);
      cd s0 = cmk(c0.x*I00.x - c0.y*I00.y + c1.x*I10.x - c1.y*I10.y,
                  c0.x*I00.y + c0.y*I00.x + c1.x*I10.y + c1.y*I10.x);
      cd s1 = cmk(c0.x*I01.x - c0.y*I01.y + c1.x*I11.x - c1.y*I11.y,
                  c0.x*I01.y + c0.y*I01.x + c1.x*I11.y + c1.y*I11.x);
      scl[threadIdx.x][0] = make_float2((float)s0.x, (float)s0.y);
      scl[threadIdx.x][1] = make_float2((float)s1.x, (float)s1.y);
    }
  }
  __syncthreads();
  for (int fl = w; fl < 32; fl += 4){
    int f = f0 + fl;
    if (f < F_){
      const float2* Wf = Wg + (size_t)f*64;
      int t = t0 + lane;
      float2 y0; y0.x=0; y0.y=0;
      float2 y1; y1.x=0; y1.y=0;
      #pragma unroll
      for (int m=0;m<8;++m){
        float2 xv = Xc[((size_t)f*8 + m)*T_ + t];
        float2 w0 = Wf[m];
        float2 w1 = Wf[8+m];
        y0.x += w0.x*xv.x - w0.y*xv.y; y0.y += w0.x*xv.y + w0.y*xv.x;
        y1.x += w1.x*xv.x - w1.y*xv.y; y1.y += w1.x*xv.y + w1.y*xv.x;
      }
      float2 s0 = scl[fl][0];
      float2 s1 = scl[fl][1];
      re0[fl][lane] = s0.x*y0.x - s0.y*y0.y; im0[fl][lane] = s0.x*y0.y + s0.y*y0.x;
      re1[fl][lane] = s1.x*y1.x - s1.y*y1.y; im1[fl][lane] = s1.x*y1.y + s1.y*y1.x;
    }
  }
  __syncthreads();
  for (int i = threadIdx.x; i < 32*64; i += 256){
    int tl = i >> 5, fl = i & 31;
    int f = f0 + fl;
    if (f < F_){
      int t = t0 + tl;
      float2 o0; o0.x = re0[fl][tl]; o0.y = im0[fl][tl];
      float2 o1; o1.x = re1[fl][tl]; o1.y = im1[fl][tl];
      out[((size_t)(0*T_ + t))*F_ + f] = o0;
      out[((size_t)(1*T_ + t))*F_ + f] = o1;
    }
  }
}

extern "C" void kernel_launch(void* const* d_in, const int* in_sizes, int n_in,
                              void* d_out, int out_size, void* d_ws, size_t ws_size,
                              hipStream_t stream) {
  const float2* Xin = (const float2*)d_in[0];
  char* ws = (char*)d_ws;
  size_t off = 0;
  auto alloc = [&](size_t bytes) -> void* {
    void* p = ws + off;
    off += (bytes + 255) & ~(size_t)255;
    return p;
  };
  float2* Xc   = (float2*)alloc((size_t)F_*M_*T_*8);
  cd*     Cp   = (cd*)alloc((size_t)F_*TS*64*16);
  cd*     Vp   = (cd*)alloc((size_t)K_*F_*TS*64*16);
  float2* W    = (float2*)alloc((size_t)F_*64*8);
  float*  part = (float*)alloc((size_t)NG*K_*T_*4);
  float*  wts2 = (float*)alloc((size_t)T_*8);
  double* dsum = (double*)alloc((size_t)F_*8);
  double* osum = (double*)alloc((size_t)F_*8);
  int*    ibuf = (int*)alloc(4096);
  if (off > ws_size) return;
  int* flags = ibuf;          // [0]=done, [1]=solve convergence ticket

  hipMemsetAsync(ibuf, 0, 4096, stream);

  pack_kernel<<<dim3(9, 64, 8), 256, 0, stream>>>(Xin, Xc);
  cov0_kernel<<<dim3(F_, TS), 512, 0, stream>>>(Xc, Cp, W);

  for (int it=0; it<NITER; ++it){
    yr_kernel<<<dim3(T_/256, NG), 256, 0, stream>>>(Xc, W, part, flags);
    rw_kernel<<<64, 256, 0, stream>>>(part, wts2, flags);
    covF_kernel<<<dim3(F_, TS), 512, 0, stream>>>(Xc, (const float2*)wts2, Vp, flags);
    updF_kernel<<<UPB, 256, 0, stream>>>(Vp, Cp, W, dsum, osum, flags);
  }

  out_kernel<<<dim3(17, 32), 256, 0, stream>>>(Xc, W, (float2*)d_out);
}